// Round 17
// baseline (112.794 us; speedup 1.0000x reference)
//
#include <hip/hip_runtime.h>
#include <stdint.h>

typedef _Float16 __attribute__((ext_vector_type(8))) f16x8;
typedef _Float16 __attribute__((ext_vector_type(4))) f16x4v;
typedef float __attribute__((ext_vector_type(4))) f32x4;
typedef float __attribute__((ext_vector_type(16))) f32x16;

__device__ __forceinline__ f32x4 mfma16(f16x8 a, f16x8 b, f32x4 c) {
  return __builtin_amdgcn_mfma_f32_16x16x32_f16(a, b, c, 0, 0, 0);
}
__device__ __forceinline__ f32x16 mfma32(f16x8 a, f16x8 b, f32x16 c) {
  return __builtin_amdgcn_mfma_f32_32x32x16_f16(a, b, c, 0, 0, 0);
}

// async global->LDS, 16B per lane. lds base wave-uniform; HW adds lane*16.
__device__ __forceinline__ void async16(void* lds, const void* g) {
  __builtin_amdgcn_global_load_lds((const __attribute__((address_space(1))) void*)g,
                                   (__attribute__((address_space(3))) void*)lds, 16, 0, 0);
}

__device__ __forceinline__ unsigned pk16(float a, float b) {
  return __builtin_bit_cast(unsigned, __builtin_amdgcn_cvt_pkrtz(a, b));
}

#define QK_PRESCALE 0.18033688011112042f  // (1/sqrt(64)) * log2(e)

// ---------------- prep: x->f16 cvt + 4 weight transposes, one launch ----------
__global__ __launch_bounds__(256) void k_prep(const float* __restrict__ x,
                                              const float* __restrict__ Wq,
                                              const float* __restrict__ Wk,
                                              const float* __restrict__ Wv,
                                              const float* __restrict__ Wo,
                                              _Float16* __restrict__ xb,
                                              _Float16* __restrict__ wqkvt,
                                              _Float16* __restrict__ wot) {
  __shared__ float tl[32][33];
  const int bid = blockIdx.x;
  if (bid < 4096) {                       // cvt: 4M f32 -> f16, float4/thread
    const int i = bid * 256 + threadIdx.x;
    const float4 v = reinterpret_cast<const float4*>(x)[i];
    f16x4v o = { (_Float16)v.x, (_Float16)v.y, (_Float16)v.z, (_Float16)v.w };
    reinterpret_cast<f16x4v*>(xb)[i] = o;
  } else {                                // transpose: 4096 blocks of 32x32
    const int i = bid - 4096;
    const int z = i >> 10, by = (i >> 5) & 31, bx = i & 31;
    const float* W = (z == 0) ? Wq : (z == 1) ? Wk : (z == 2) ? Wv : Wo;
    _Float16* dst = (z < 3) ? (wqkvt + ((size_t)z << 20)) : wot;
    const int c0 = bx * 32, r0 = by * 32;
    const int tx = threadIdx.x & 31, ty = threadIdx.x >> 5;  // 32 x 8
#pragma unroll
    for (int q = 0; q < 32; q += 8)
      tl[ty + q][tx] = W[(size_t)(r0 + ty + q) * 1024 + c0 + tx];
    __syncthreads();
#pragma unroll
    for (int q = 0; q < 32; q += 8)
      dst[(size_t)(c0 + ty + q) * 1024 + r0 + tx] = (_Float16)tl[tx][ty + q];
  }
}

// ---------------- QKV GEMM: big-tile 2-phase, COALESCED swizzled staging -------
// C[4096][3072] = xb @ [Wq^T;Wk^T;Wv^T]^T. BM=256, BN=192, BK=64, 8 waves
// (2M x 4N), wave tile 128x48 -> 48 mfma16/barrier/wave; 16 K-tiles.
// Grid 256 = exactly 1/CU. LDS 112 KB (1 blk/CU).
// Staging (validated R15 recipe, 8 chunks/row): lane=(row=l>>3, qs=l&7); slot
// (row,qs) holds global chunk qs^((row>>1)&7); 4 lanes/64B line. Read chunk c
// at row r -> slot r*8 + (c^((r>>1)&7)); 16-lane groups hit each bank-group
// twice = 2-way = free. Epilogue: col<1024 Q prescale; <2048 K; else V^T scatter.
__global__ __launch_bounds__(512) void k_qkv(const _Float16* __restrict__ A,
                                             const _Float16* __restrict__ Bt,
                                             _Float16* __restrict__ qkb,
                                             _Float16* __restrict__ vtb) {
  __shared__ _Float16 As[2][16384];   // [256 rows][8 chunks][8 f16] swizzled
  __shared__ _Float16 Bs[2][12288];   // [192 rows][8 chunks][8 f16] swizzled
  constexpr int K = 1024;
  const int bid = blockIdx.x;                       // 256 blocks
  const int swz = (bid & 7) * 32 + (bid >> 3);      // bijective XCD chunks
  const int tile_n = (swz & 15) * 192;
  const int tile_m = (swz >> 4) * 256;
  const int t = threadIdx.x;
  const int w = t >> 6, lane = t & 63;
  const int c16 = lane & 15, g16 = lane >> 4;
  const int wm = w >> 2, wn = w & 3;                // 2M x 4N

  f32x4 acc[8][3] = {};

  // per-lane staging offsets, hoisted (only k0 varies per iter)
  const int rl = lane >> 3, qc = lane & 7;
  size_t aoff[4], boff[3];
#pragma unroll
  for (int q = 0; q < 4; ++q) {
    const int row = w * 32 + q * 8 + rl;
    aoff[q] = (size_t)(tile_m + row) * K + (qc ^ ((row >> 1) & 7)) * 8;
  }
#pragma unroll
  for (int q = 0; q < 3; ++q) {
    const int row = w * 24 + q * 8 + rl;
    boff[q] = (size_t)(tile_n + row) * K + (qc ^ ((row >> 1) & 7)) * 8;
  }

  auto stage = [&](int buf, int k0) {
#pragma unroll
    for (int q = 0; q < 4; ++q)
      async16(&As[buf][(w * 256 + q * 64) * 8], A + aoff[q] + k0);
#pragma unroll
    for (int q = 0; q < 3; ++q)
      async16(&Bs[buf][(w * 192 + q * 64) * 8], Bt + boff[q] + k0);
  };

  stage(0, 0);
  for (int kt = 0; kt < 16; ++kt) {
    const int buf = kt & 1;
    __syncthreads();                     // stage(kt) drained; prev reads done
    if (kt + 1 < 16) stage(buf ^ 1, (kt + 1) << 6);
#pragma unroll
    for (int ks = 0; ks < 2; ++ks) {     // two K=32 halves
      const int c = ks * 4 + g16;        // k-chunk 0..7
      f16x8 af[8], bf[3];
#pragma unroll
      for (int i = 0; i < 8; ++i) {
        const int r = wm * 128 + i * 16 + c16;
        af[i] = *reinterpret_cast<const f16x8*>(&As[buf][(r * 8 + (c ^ ((r >> 1) & 7))) * 8]);
      }
#pragma unroll
      for (int j = 0; j < 3; ++j) {
        const int r = wn * 48 + j * 16 + c16;
        bf[j] = *reinterpret_cast<const f16x8*>(&Bs[buf][(r * 8 + (c ^ ((r >> 1) & 7))) * 8]);
      }
      __builtin_amdgcn_s_setprio(1);
#pragma unroll
      for (int i = 0; i < 8; ++i)
#pragma unroll
        for (int j = 0; j < 3; ++j) acc[i][j] = mfma16(af[i], bf[j], acc[i][j]);
      __builtin_amdgcn_s_setprio(0);
    }
  }

  // D layout: col = lane&15, row = (lane>>4)*4 + reg
#pragma unroll
  for (int i = 0; i < 8; ++i) {
#pragma unroll
    for (int j = 0; j < 3; ++j) {
      const int col = tile_n + wn * 48 + j * 16 + c16;
#pragma unroll
      for (int r = 0; r < 4; ++r) {
        const int row = tile_m + wm * 128 + i * 16 + g16 * 4 + r;
        float v = acc[i][j][r];
        if (col < 2048) {
          if (col < 1024) v *= QK_PRESCALE;    // fold softmax scale into Q
          qkb[(size_t)row * 2048 + col] = (_Float16)v;
        } else {
          const int dd = col - 2048;           // h*64 + d
          vtb[((size_t)(row >> 11) * 1024 + dd) * 2048 + (row & 2047)] = (_Float16)v;
        }
      }
    }
  }
}

// ---------------- O-gemm: BK=64, coalesced swizzled staging -------------------
// 128x64 tile, 512 blocks (2/CU at 48 KB LDS), 16 iters x 16 mfma/wave.
__global__ __launch_bounds__(256) void k_out(const _Float16* __restrict__ ctx,
                                             const _Float16* __restrict__ wot,
                                             const float* __restrict__ bias,
                                             float* __restrict__ out) {
  __shared__ _Float16 As[2][8192];    // [128 rows][8 chunks][8 f16] swizzled
  __shared__ _Float16 Bs[2][4096];    // [64 rows][8 chunks][8 f16] swizzled
  const int bid = blockIdx.x;                    // 512
  const int swz = (bid & 7) * 64 + (bid >> 3);
  const int tile_n = (swz & 15) * 64;
  const int tile_m = (swz >> 4) * 128;
  const int K = 1024;
  const int t = threadIdx.x;
  const int w = t >> 6, lane = t & 63;
  const int c16 = lane & 15, g16 = lane >> 4;
  const int wr = (w >> 1) * 64, wc = (w & 1) * 32;

  f32x4 acc[4][2] = {};

  const int rl = lane >> 3, qc = lane & 7;
  size_t aoff[4], boff[2];
#pragma unroll
  for (int q = 0; q < 4; ++q) {
    const int row = w * 32 + q * 8 + rl;
    aoff[q] = (size_t)(tile_m + row) * K + (qc ^ ((row >> 1) & 7)) * 8;
  }
#pragma unroll
  for (int q = 0; q < 2; ++q) {
    const int row = w * 16 + q * 8 + rl;
    boff[q] = (size_t)(tile_n + row) * K + (qc ^ ((row >> 1) & 7)) * 8;
  }

  auto stage = [&](int buf, int k0) {
#pragma unroll
    for (int q = 0; q < 4; ++q)
      async16(&As[buf][(w * 256 + q * 64) * 8], ctx + aoff[q] + k0);
#pragma unroll
    for (int q = 0; q < 2; ++q)
      async16(&Bs[buf][(w * 128 + q * 64) * 8], wot + boff[q] + k0);
  };

  stage(0, 0);
  for (int kt = 0; kt < 16; ++kt) {
    const int buf = kt & 1;
    __syncthreads();
    if (kt + 1 < 16) stage(buf ^ 1, (kt + 1) << 6);
#pragma unroll
    for (int ks = 0; ks < 2; ++ks) {
      const int c = ks * 4 + g16;
      f16x8 af[4], bf[2];
#pragma unroll
      for (int i = 0; i < 4; ++i) {
        const int r = wr + i * 16 + c16;
        af[i] = *reinterpret_cast<const f16x8*>(&As[buf][(r * 8 + (c ^ ((r >> 1) & 7))) * 8]);
      }
#pragma unroll
      for (int j = 0; j < 2; ++j) {
        const int r = wc + j * 16 + c16;
        bf[j] = *reinterpret_cast<const f16x8*>(&Bs[buf][(r * 8 + (c ^ ((r >> 1) & 7))) * 8]);
      }
#pragma unroll
      for (int i = 0; i < 4; ++i)
#pragma unroll
        for (int j = 0; j < 2; ++j) acc[i][j] = mfma16(af[i], bf[j], acc[i][j]);
    }
  }

#pragma unroll
  for (int i = 0; i < 4; ++i) {
#pragma unroll
    for (int j = 0; j < 2; ++j) {
      const int col = tile_n + wc + j * 16 + c16;
#pragma unroll
      for (int r = 0; r < 4; ++r) {
        const int row = tile_m + wr + i * 16 + g16 * 4 + r;
        out[(size_t)row * 1024 + col] = acc[i][j][r] + bias[col];
      }
    }
  }
}

// ---------------- causal attention: paired block, COALESCED K/V staging -------
// (unchanged from R16 — validated)
__global__ __launch_bounds__(512, 4) void k_attn_pair(const _Float16* __restrict__ qk,
                                                      const _Float16* __restrict__ vt,
                                                      _Float16* __restrict__ ctx) {
  const int fid = blockIdx.x;                 // 512 blocks = 2/CU, all resident
  const int lid = fid & 255, half = fid >> 8;
  const int xcd = lid & 7, g = lid >> 3;      // g in [0,32)
  const int bh = xcd + 8 * (g & 3);           // 4 bh per XCD -> K/V/Q L2-resident
  const int p = g >> 2;                       // [0,8)
  const int pr = half ? (15 - p) : p;         // CU slot pairs pr=p with 15-p: uniform
  const int a = 31 - pr;
  const int b = bh >> 4, h = bh & 15;

  const int t = threadIdx.x, w = t >> 6, lane = t & 63;
  const int li = lane & 31, h8 = lane >> 5;
  const int qs = w >> 1, par = w & 1;
  const int qt = (qs < 2) ? (2 * a + (qs & 1)) : (2 * pr + (qs & 1));

  const _Float16* Qp = qk + ((size_t)b << 22) + (h << 6);
  const _Float16* Kp = Qp + 1024;
  const _Float16* Vt = vt + ((((size_t)b << 10) + (size_t)(h << 6)) << 11);

  __shared__ _Float16 Kl[2][4096];   // [cg2][row64][cc4][8f16] swizzled
  __shared__ _Float16 Vl[2][4096];   // [cg2][d64][cc4][8f16]  swizzled
  __shared__ _Float16 Cb[4][32][68]; // pair-combine O (padded rows)
  __shared__ float Cl[4][32];        // pair-combine l

  const int qrow = qt * 32 + li;
  f16x8 qf[4];
#pragma unroll
  for (int mm = 0; mm < 4; ++mm)
    qf[mm] = *reinterpret_cast<const f16x8*>(Qp + (size_t)qrow * 2048 + mm * 16 + h8 * 8);

  // coalesced stage: wave w -> rows (w&3)*16..+15, chunk-group cg=w>>2
  const int srg = w & 3, scg = w >> 2;
  const int srl = lane >> 2;                           // row within group
  const int srowk = srg * 16 + srl;                    // tile row 0..63
  const int sc = scg * 4 + ((lane & 3) ^ ((srl >> 1) & 3));  // pre-swz 16B chunk
  auto stage = [&](int buf, int s) {
    const int kb = s << 6;
    async16(&Kl[buf][(scg * 256 + srg * 64) * 8],
            Kp + (size_t)(kb + srowk) * 2048 + sc * 8);
    async16(&Vl[buf][(scg * 256 + srg * 64) * 8],
            Vt + (size_t)srowk * 2048 + kb + sc * 8);
  };

  const int rkey = (li >> 1) & 3;                      // read-side swizzle key

  f32x16 oa0, oa1;
#pragma unroll
  for (int r = 0; r < 16; ++r) { oa0[r] = 0.f; oa1[r] = 0.f; }
  float la0 = 0.f, la1 = 0.f;

  stage(0, 0);
  for (int s = 0; s <= a; ++s) {
    const int buf = s & 1;
    __syncthreads();                    // staged buf ready; prev buf reads done
    if (s < a) stage(buf ^ 1, s + 1);   // prefetch overlaps compute
    const int j = 2 * s + par;
    if (j <= qt) {
      f32x16 st;
#pragma unroll
      for (int r = 0; r < 16; ++r) st[r] = 0.f;
#pragma unroll
      for (int mm = 0; mm < 4; ++mm) {
        const int c = mm * 2 + h8;
        const int slot = ((c >> 2) << 8) + (par * 32 + li) * 4 + ((c & 3) ^ rkey);
        const f16x8 kf = *reinterpret_cast<const f16x8*>(&Kl[buf][slot * 8]);
        st = mfma32(kf, qf[mm], st);
      }
      if (j == qt) {  // diagonal sub-tile: causal mask
#pragma unroll
        for (int r = 0; r < 16; ++r) {
          const int kloc = (r & 3) + ((r >> 2) << 3) + (h8 << 2);
          if (kloc > li) st[r] = -1000.f;
        }
      }
      unsigned G[8];
#pragma unroll
      for (int jj = 0; jj < 8; ++jj) {
        const float p0 = __builtin_amdgcn_exp2f(st[2 * jj]);
        const float p1 = __builtin_amdgcn_exp2f(st[2 * jj + 1]);
        if (jj & 1) la1 += p0 + p1; else la0 += p0 + p1;
        G[jj] = pk16(p0, p1);
      }
#pragma unroll
      for (int chunk = 0; chunk < 2; ++chunk) {
        const unsigned g0 = G[chunk * 4 + 0], g1 = G[chunk * 4 + 1];
        const unsigned g2 = G[chunk * 4 + 2], g3 = G[chunk * 4 + 3];
        const unsigned s02 = __shfl_xor(h8 ? g0 : g2, 32);
        const unsigned s13 = __shfl_xor(h8 ? g1 : g3, 32);
        union { unsigned u[4]; f16x8 v; } pb;
        pb.u[0] = h8 ? s02 : g0;
        pb.u[1] = h8 ? s13 : g1;
        pb.u[2] = h8 ? g2 : s02;
        pb.u[3] = h8 ? g3 : s13;
        const int c0 = par * 4 + chunk * 2 + h8;
        const int sv0 = ((c0 >> 2) << 8) + li * 4 + ((c0 & 3) ^ rkey);
        const int sv1 = sv0 + 128;     // row +32, same key
        const f16x8 vf0 = *reinterpret_cast<const f16x8*>(&Vl[buf][sv0 * 8]);
        const f16x8 vf1 = *reinterpret_cast<const f16x8*>(&Vl[buf][sv1 * 8]);
        oa0 = mfma32(vf0, pb.v, oa0);
        oa1 = mfma32(vf1, pb.v, oa1);
      }
    }
  }

  float lsum = la0 + la1;
  lsum += __shfl_xor(lsum, 32);
  __syncthreads();                       // last compute reads done before Cb reuse
  if (par) {
#pragma unroll
    for (int rr = 0; rr < 4; ++rr) {
      uint2 p0, p1;
      p0.x = pk16(oa0[rr * 4 + 0], oa0[rr * 4 + 1]);
      p0.y = pk16(oa0[rr * 4 + 2], oa0[rr * 4 + 3]);
      p1.x = pk16(oa1[rr * 4 + 0], oa1[rr * 4 + 1]);
      p1.y = pk16(oa1[rr * 4 + 2], oa1[rr * 4 + 3]);
      *reinterpret_cast<uint2*>(&Cb[qs][li][rr * 8 + h8 * 4]) = p0;
      *reinterpret_cast<uint2*>(&Cb[qs][li][32 + rr * 8 + h8 * 4]) = p1;
    }
    if (!h8) Cl[qs][li] = lsum;
  }
  __syncthreads();
  if (!par) {
    const float lt = lsum + Cl[qs][li];
    const float rl = 1.f / lt;
    _Float16* crow = ctx + ((size_t)(b * 2048 + qrow) << 10) + h * 64;
#pragma unroll
    for (int rr = 0; rr < 4; ++rr) {
      const f16x4v q0 = *reinterpret_cast<const f16x4v*>(&Cb[qs][li][rr * 8 + h8 * 4]);
      const f16x4v q1 = *reinterpret_cast<const f16x4v*>(&Cb[qs][li][32 + rr * 8 + h8 * 4]);
      uint2 o0, o1;
      o0.x = pk16((oa0[rr * 4 + 0] + (float)q0[0]) * rl, (oa0[rr * 4 + 1] + (float)q0[1]) * rl);
      o0.y = pk16((oa0[rr * 4 + 2] + (float)q0[2]) * rl, (oa0[rr * 4 + 3] + (float)q0[3]) * rl);
      o1.x = pk16((oa1[rr * 4 + 0] + (float)q1[0]) * rl, (oa1[rr * 4 + 1] + (float)q1[1]) * rl);
      o1.y = pk16((oa1[rr * 4 + 2] + (float)q1[2]) * rl, (oa1[rr * 4 + 3] + (float)q1[3]) * rl);
      *reinterpret_cast<uint2*>(crow + rr * 8 + h8 * 4) = o0;
      *reinterpret_cast<uint2*>(crow + 32 + rr * 8 + h8 * 4) = o1;
    }
  }
}

// ---------------- launcher ----------------
extern "C" void kernel_launch(void* const* d_in, const int* in_sizes, int n_in,
                              void* d_out, int out_size, void* d_ws, size_t ws_size,
                              hipStream_t stream) {
  (void)in_sizes; (void)n_in; (void)out_size; (void)ws_size;
  const float* x  = (const float*)d_in[0];
  const float* Wq = (const float*)d_in[1];
  const float* Wk = (const float*)d_in[2];
  const float* Wv = (const float*)d_in[3];
  const float* Wo = (const float*)d_in[4];
  const float* bo = (const float*)d_in[5];
  float* out = (float*)d_out;

  char* ws = (char*)d_ws;
  _Float16* xb    = (_Float16*)(ws);                 //  8 MB  x f16 [4096][1024]
  _Float16* wqkvt = (_Float16*)(ws + (8u  << 20));   //  6 MB  [Wq^T;Wk^T;Wv^T]
  _Float16* wot   = (_Float16*)(ws + (14u << 20));   //  2 MB  Wo^T
  _Float16* qkb   = (_Float16*)(ws + (16u << 20));   // 16 MB  QK [4096][2048]
  _Float16* vtb   = (_Float16*)(ws + (32u << 20));   //  8 MB  V^T [2][1024][2048]
  _Float16* ctx   = (_Float16*)(ws + (40u << 20));   //  8 MB  ctx [4096][1024]

  k_prep<<<8192, 256, 0, stream>>>(x, Wq, Wk, Wv, Wo, xb, wqkvt, wot);
  k_qkv<<<256, 512, 0, stream>>>(xb, wqkvt, qkb, vtb);
  k_attn_pair<<<512, 512, 0, stream>>>(qkb, vtb, ctx);
  k_out<<<512, 256, 0, stream>>>(ctx, wot, bo, out);
}

// Round 18
// 106.882 us; speedup vs baseline: 1.0553x; 1.0553x over previous
//
#include <hip/hip_runtime.h>
#include <stdint.h>

typedef _Float16 __attribute__((ext_vector_type(8))) f16x8;
typedef _Float16 __attribute__((ext_vector_type(4))) f16x4v;
typedef float __attribute__((ext_vector_type(4))) f32x4;
typedef float __attribute__((ext_vector_type(16))) f32x16;

__device__ __forceinline__ f32x4 mfma16(f16x8 a, f16x8 b, f32x4 c) {
  return __builtin_amdgcn_mfma_f32_16x16x32_f16(a, b, c, 0, 0, 0);
}
__device__ __forceinline__ f32x16 mfma32(f16x8 a, f16x8 b, f32x16 c) {
  return __builtin_amdgcn_mfma_f32_32x32x16_f16(a, b, c, 0, 0, 0);
}

// async global->LDS, 16B per lane. lds base wave-uniform; HW adds lane*16.
__device__ __forceinline__ void async16(void* lds, const void* g) {
  __builtin_amdgcn_global_load_lds((const __attribute__((address_space(1))) void*)g,
                                   (__attribute__((address_space(3))) void*)lds, 16, 0, 0);
}

__device__ __forceinline__ unsigned pk16(float a, float b) {
  return __builtin_bit_cast(unsigned, __builtin_amdgcn_cvt_pkrtz(a, b));
}

#define QK_PRESCALE 0.18033688011112042f  // (1/sqrt(64)) * log2(e)

// ---------------- prep: x->f16 cvt + 4 weight transposes, one launch ----------
__global__ __launch_bounds__(256) void k_prep(const float* __restrict__ x,
                                              const float* __restrict__ Wq,
                                              const float* __restrict__ Wk,
                                              const float* __restrict__ Wv,
                                              const float* __restrict__ Wo,
                                              _Float16* __restrict__ xb,
                                              _Float16* __restrict__ wqkvt,
                                              _Float16* __restrict__ wot) {
  __shared__ float tl[32][33];
  const int bid = blockIdx.x;
  if (bid < 4096) {                       // cvt: 4M f32 -> f16, float4/thread
    const int i = bid * 256 + threadIdx.x;
    const float4 v = reinterpret_cast<const float4*>(x)[i];
    f16x4v o = { (_Float16)v.x, (_Float16)v.y, (_Float16)v.z, (_Float16)v.w };
    reinterpret_cast<f16x4v*>(xb)[i] = o;
  } else {                                // transpose: 4096 blocks of 32x32
    const int i = bid - 4096;
    const int z = i >> 10, by = (i >> 5) & 31, bx = i & 31;
    const float* W = (z == 0) ? Wq : (z == 1) ? Wk : (z == 2) ? Wv : Wo;
    _Float16* dst = (z < 3) ? (wqkvt + ((size_t)z << 20)) : wot;
    const int c0 = bx * 32, r0 = by * 32;
    const int tx = threadIdx.x & 31, ty = threadIdx.x >> 5;  // 32 x 8
#pragma unroll
    for (int q = 0; q < 32; q += 8)
      tl[ty + q][tx] = W[(size_t)(r0 + ty + q) * 1024 + c0 + tx];
    __syncthreads();
#pragma unroll
    for (int q = 0; q < 32; q += 8)
      dst[(size_t)(c0 + ty + q) * 1024 + r0 + tx] = (_Float16)tl[tx][ty + q];
  }
}

// ---------------- fused QK-gemm + V-gemm, COALESCED staging (R15 proven) -----
// 128x128 tile, BK=32, 4 waves, 2-buffer 1-barrier, 768 blocks = 3/CU.
// Measured: 48.6us, 530 TF, MfmaUtil 21%, 0 bank conflicts.
__global__ __launch_bounds__(256) void k_qkv(const _Float16* __restrict__ xb,
                                             const _Float16* __restrict__ wqkvt,
                                             _Float16* __restrict__ qkb,
                                             _Float16* __restrict__ vtb) {
  __shared__ _Float16 As[2][4096];
  __shared__ _Float16 Bs[2][4096];
  const int bid = blockIdx.x;
  const _Float16 *A, *Bt;
  int tile_m, tile_n, role;
  if (bid < 512) {                       // QK: M=4096, N=2048
    const int swz = (bid & 7) * 64 + (bid >> 3);   // bijective XCD chunks
    tile_n = (swz & 15) * 128;
    tile_m = (swz >> 4) * 128;
    A = xb; Bt = wqkvt; role = 0;
  } else {                               // V: M=1024 (dd), N=4096 (b*2048+row)
    const int f = bid - 512;
    const int swz = (f & 7) * 32 + (f >> 3);
    tile_n = (swz & 31) * 128;
    tile_m = (swz >> 5) * 128;
    A = wqkvt + (2u << 20); Bt = xb; role = 1;
  }
  const int K = 1024;
  const int t = threadIdx.x;
  const int w = t >> 6, lane = t & 63;
  const int c16 = lane & 15, g = lane >> 4;
  const int wr = (w >> 1) * 64, wc = (w & 1) * 64;
  const int skey = (c16 >> 1) & 3;                 // read-side swizzle key

  f32x4 acc[4][4] = {};

  const int srow = lane >> 2;                      // 0..15 within 16-row group
  const int sgg = (lane & 3) ^ ((lane >> 3) & 3);  // pre-swizzled chunk

  auto stage = [&](int buf, int k0) {
#pragma unroll
    for (int i = 0; i < 2; ++i) {
      const int row = i * 64 + w * 16 + srow;      // tile row
      async16(&As[buf][(i * 256 + w * 64) * 8],
              A + (size_t)(tile_m + row) * K + k0 + sgg * 8);
      async16(&Bs[buf][(i * 256 + w * 64) * 8],
              Bt + (size_t)(tile_n + row) * K + k0 + sgg * 8);
    }
  };

  stage(0, 0);
  for (int it = 0; it < 32; ++it) {
    const int buf = it & 1;
    __syncthreads();
    if (it + 1 < 32) stage(buf ^ 1, (it + 1) << 5);
    f16x8 af[4], bf[4];
#pragma unroll
    for (int i = 0; i < 4; ++i) {
      const int ra = wr + i * 16 + c16, rb = wc + i * 16 + c16;
      af[i] = *reinterpret_cast<const f16x8*>(&As[buf][(ra * 4 + (g ^ skey)) * 8]);
      bf[i] = *reinterpret_cast<const f16x8*>(&Bs[buf][(rb * 4 + (g ^ skey)) * 8]);
    }
#pragma unroll
    for (int i = 0; i < 4; ++i)
#pragma unroll
      for (int j = 0; j < 4; ++j) acc[i][j] = mfma16(af[i], bf[j], acc[i][j]);
  }

  // D layout: col = lane&15, row = (lane>>4)*4 + reg
#pragma unroll
  for (int i = 0; i < 4; ++i) {
#pragma unroll
    for (int j = 0; j < 4; ++j) {
      const int colb = tile_n + wc + j * 16;
#pragma unroll
      for (int r = 0; r < 4; ++r) {
        const int row = tile_m + wr + i * 16 + g * 4 + r;
        const int col = colb + c16;
        float v = acc[i][j][r];
        if (role == 0) {
          if (col < 1024) v *= QK_PRESCALE;    // fold softmax scale into Q
          qkb[(size_t)row * 2048 + col] = (_Float16)v;
        } else {
          vtb[((size_t)(col >> 11) << 21) + (size_t)row * 2048 + (col & 2047)] = (_Float16)v;
        }
      }
    }
  }
}

// ---------------- O-gemm: BK=64, coalesced swizzled staging (R17) -------------
// 128x64 tile, 512 blocks (3/CU at 48 KB LDS), 16 iters x 16 mfma/wave.
__global__ __launch_bounds__(256) void k_out(const _Float16* __restrict__ ctx,
                                             const _Float16* __restrict__ wot,
                                             const float* __restrict__ bias,
                                             float* __restrict__ out) {
  __shared__ _Float16 As[2][8192];    // [128 rows][8 chunks][8 f16] swizzled
  __shared__ _Float16 Bs[2][4096];    // [64 rows][8 chunks][8 f16] swizzled
  const int bid = blockIdx.x;                    // 512
  const int swz = (bid & 7) * 64 + (bid >> 3);
  const int tile_n = (swz & 15) * 64;
  const int tile_m = (swz >> 4) * 128;
  const int K = 1024;
  const int t = threadIdx.x;
  const int w = t >> 6, lane = t & 63;
  const int c16 = lane & 15, g16 = lane >> 4;
  const int wr = (w >> 1) * 64, wc = (w & 1) * 32;

  f32x4 acc[4][2] = {};

  const int rl = lane >> 3, qc = lane & 7;
  size_t aoff[4], boff[2];
#pragma unroll
  for (int q = 0; q < 4; ++q) {
    const int row = w * 32 + q * 8 + rl;
    aoff[q] = (size_t)(tile_m + row) * K + (qc ^ ((row >> 1) & 7)) * 8;
  }
#pragma unroll
  for (int q = 0; q < 2; ++q) {
    const int row = w * 16 + q * 8 + rl;
    boff[q] = (size_t)(tile_n + row) * K + (qc ^ ((row >> 1) & 7)) * 8;
  }

  auto stage = [&](int buf, int k0) {
#pragma unroll
    for (int q = 0; q < 4; ++q)
      async16(&As[buf][(w * 256 + q * 64) * 8], ctx + aoff[q] + k0);
#pragma unroll
    for (int q = 0; q < 2; ++q)
      async16(&Bs[buf][(w * 128 + q * 64) * 8], wot + boff[q] + k0);
  };

  stage(0, 0);
  for (int kt = 0; kt < 16; ++kt) {
    const int buf = kt & 1;
    __syncthreads();
    if (kt + 1 < 16) stage(buf ^ 1, (kt + 1) << 6);
#pragma unroll
    for (int ks = 0; ks < 2; ++ks) {
      const int c = ks * 4 + g16;
      f16x8 af[4], bf[2];
#pragma unroll
      for (int i = 0; i < 4; ++i) {
        const int r = wr + i * 16 + c16;
        af[i] = *reinterpret_cast<const f16x8*>(&As[buf][(r * 8 + (c ^ ((r >> 1) & 7))) * 8]);
      }
#pragma unroll
      for (int j = 0; j < 2; ++j) {
        const int r = wc + j * 16 + c16;
        bf[j] = *reinterpret_cast<const f16x8*>(&Bs[buf][(r * 8 + (c ^ ((r >> 1) & 7))) * 8]);
      }
#pragma unroll
      for (int i = 0; i < 4; ++i)
#pragma unroll
        for (int j = 0; j < 2; ++j) acc[i][j] = mfma16(af[i], bf[j], acc[i][j]);
    }
  }

#pragma unroll
  for (int i = 0; i < 4; ++i) {
#pragma unroll
    for (int j = 0; j < 2; ++j) {
      const int col = tile_n + wc + j * 16 + c16;
#pragma unroll
      for (int r = 0; r < 4; ++r) {
        const int row = tile_m + wr + i * 16 + g16 * 4 + r;
        out[(size_t)row * 1024 + col] = acc[i][j][r] + bias[col];
      }
    }
  }
}

// ---------------- causal attention: paired block, COALESCED K/V staging -------
// (unchanged from R16 — validated)
__global__ __launch_bounds__(512, 4) void k_attn_pair(const _Float16* __restrict__ qk,
                                                      const _Float16* __restrict__ vt,
                                                      _Float16* __restrict__ ctx) {
  const int fid = blockIdx.x;                 // 512 blocks = 2/CU, all resident
  const int lid = fid & 255, half = fid >> 8;
  const int xcd = lid & 7, g = lid >> 3;      // g in [0,32)
  const int bh = xcd + 8 * (g & 3);           // 4 bh per XCD -> K/V/Q L2-resident
  const int p = g >> 2;                       // [0,8)
  const int pr = half ? (15 - p) : p;         // CU slot pairs pr=p with 15-p: uniform
  const int a = 31 - pr;
  const int b = bh >> 4, h = bh & 15;

  const int t = threadIdx.x, w = t >> 6, lane = t & 63;
  const int li = lane & 31, h8 = lane >> 5;
  const int qs = w >> 1, par = w & 1;
  const int qt = (qs < 2) ? (2 * a + (qs & 1)) : (2 * pr + (qs & 1));

  const _Float16* Qp = qk + ((size_t)b << 22) + (h << 6);
  const _Float16* Kp = Qp + 1024;
  const _Float16* Vt = vt + ((((size_t)b << 10) + (size_t)(h << 6)) << 11);

  __shared__ _Float16 Kl[2][4096];   // [cg2][row64][cc4][8f16] swizzled
  __shared__ _Float16 Vl[2][4096];   // [cg2][d64][cc4][8f16]  swizzled
  __shared__ _Float16 Cb[4][32][68]; // pair-combine O (padded rows)
  __shared__ float Cl[4][32];        // pair-combine l

  const int qrow = qt * 32 + li;
  f16x8 qf[4];
#pragma unroll
  for (int mm = 0; mm < 4; ++mm)
    qf[mm] = *reinterpret_cast<const f16x8*>(Qp + (size_t)qrow * 2048 + mm * 16 + h8 * 8);

  // coalesced stage: wave w -> rows (w&3)*16..+15, chunk-group cg=w>>2
  const int srg = w & 3, scg = w >> 2;
  const int srl = lane >> 2;                           // row within group
  const int srowk = srg * 16 + srl;                    // tile row 0..63
  const int sc = scg * 4 + ((lane & 3) ^ ((srl >> 1) & 3));  // pre-swz 16B chunk
  auto stage = [&](int buf, int s) {
    const int kb = s << 6;
    async16(&Kl[buf][(scg * 256 + srg * 64) * 8],
            Kp + (size_t)(kb + srowk) * 2048 + sc * 8);
    async16(&Vl[buf][(scg * 256 + srg * 64) * 8],
            Vt + (size_t)srowk * 2048 + kb + sc * 8);
  };

  const int rkey = (li >> 1) & 3;                      // read-side swizzle key

  f32x16 oa0, oa1;
#pragma unroll
  for (int r = 0; r < 16; ++r) { oa0[r] = 0.f; oa1[r] = 0.f; }
  float la0 = 0.f, la1 = 0.f;

  stage(0, 0);
  for (int s = 0; s <= a; ++s) {
    const int buf = s & 1;
    __syncthreads();                    // staged buf ready; prev buf reads done
    if (s < a) stage(buf ^ 1, s + 1);   // prefetch overlaps compute
    const int j = 2 * s + par;
    if (j <= qt) {
      f32x16 st;
#pragma unroll
      for (int r = 0; r < 16; ++r) st[r] = 0.f;
#pragma unroll
      for (int mm = 0; mm < 4; ++mm) {
        const int c = mm * 2 + h8;
        const int slot = ((c >> 2) << 8) + (par * 32 + li) * 4 + ((c & 3) ^ rkey);
        const f16x8 kf = *reinterpret_cast<const f16x8*>(&Kl[buf][slot * 8]);
        st = mfma32(kf, qf[mm], st);
      }
      if (j == qt) {  // diagonal sub-tile: causal mask
#pragma unroll
        for (int r = 0; r < 16; ++r) {
          const int kloc = (r & 3) + ((r >> 2) << 3) + (h8 << 2);
          if (kloc > li) st[r] = -1000.f;
        }
      }
      unsigned G[8];
#pragma unroll
      for (int jj = 0; jj < 8; ++jj) {
        const float p0 = __builtin_amdgcn_exp2f(st[2 * jj]);
        const float p1 = __builtin_amdgcn_exp2f(st[2 * jj + 1]);
        if (jj & 1) la1 += p0 + p1; else la0 += p0 + p1;
        G[jj] = pk16(p0, p1);
      }
#pragma unroll
      for (int chunk = 0; chunk < 2; ++chunk) {
        const unsigned g0 = G[chunk * 4 + 0], g1 = G[chunk * 4 + 1];
        const unsigned g2 = G[chunk * 4 + 2], g3 = G[chunk * 4 + 3];
        const unsigned s02 = __shfl_xor(h8 ? g0 : g2, 32);
        const unsigned s13 = __shfl_xor(h8 ? g1 : g3, 32);
        union { unsigned u[4]; f16x8 v; } pb;
        pb.u[0] = h8 ? s02 : g0;
        pb.u[1] = h8 ? s13 : g1;
        pb.u[2] = h8 ? g2 : s02;
        pb.u[3] = h8 ? g3 : s13;
        const int c0 = par * 4 + chunk * 2 + h8;
        const int sv0 = ((c0 >> 2) << 8) + li * 4 + ((c0 & 3) ^ rkey);
        const int sv1 = sv0 + 128;     // row +32, same key
        const f16x8 vf0 = *reinterpret_cast<const f16x8*>(&Vl[buf][sv0 * 8]);
        const f16x8 vf1 = *reinterpret_cast<const f16x8*>(&Vl[buf][sv1 * 8]);
        oa0 = mfma32(vf0, pb.v, oa0);
        oa1 = mfma32(vf1, pb.v, oa1);
      }
    }
  }

  float lsum = la0 + la1;
  lsum += __shfl_xor(lsum, 32);
  __syncthreads();                       // last compute reads done before Cb reuse
  if (par) {
#pragma unroll
    for (int rr = 0; rr < 4; ++rr) {
      uint2 p0, p1;
      p0.x = pk16(oa0[rr * 4 + 0], oa0[rr * 4 + 1]);
      p0.y = pk16(oa0[rr * 4 + 2], oa0[rr * 4 + 3]);
      p1.x = pk16(oa1[rr * 4 + 0], oa1[rr * 4 + 1]);
      p1.y = pk16(oa1[rr * 4 + 2], oa1[rr * 4 + 3]);
      *reinterpret_cast<uint2*>(&Cb[qs][li][rr * 8 + h8 * 4]) = p0;
      *reinterpret_cast<uint2*>(&Cb[qs][li][32 + rr * 8 + h8 * 4]) = p1;
    }
    if (!h8) Cl[qs][li] = lsum;
  }
  __syncthreads();
  if (!par) {
    const float lt = lsum + Cl[qs][li];
    const float rl = 1.f / lt;
    _Float16* crow = ctx + ((size_t)(b * 2048 + qrow) << 10) + h * 64;
#pragma unroll
    for (int rr = 0; rr < 4; ++rr) {
      const f16x4v q0 = *reinterpret_cast<const f16x4v*>(&Cb[qs][li][rr * 8 + h8 * 4]);
      const f16x4v q1 = *reinterpret_cast<const f16x4v*>(&Cb[qs][li][32 + rr * 8 + h8 * 4]);
      uint2 o0, o1;
      o0.x = pk16((oa0[rr * 4 + 0] + (float)q0[0]) * rl, (oa0[rr * 4 + 1] + (float)q0[1]) * rl);
      o0.y = pk16((oa0[rr * 4 + 2] + (float)q0[2]) * rl, (oa0[rr * 4 + 3] + (float)q0[3]) * rl);
      o1.x = pk16((oa1[rr * 4 + 0] + (float)q1[0]) * rl, (oa1[rr * 4 + 1] + (float)q1[1]) * rl);
      o1.y = pk16((oa1[rr * 4 + 2] + (float)q1[2]) * rl, (oa1[rr * 4 + 3] + (float)q1[3]) * rl);
      *reinterpret_cast<uint2*>(crow + rr * 8 + h8 * 4) = o0;
      *reinterpret_cast<uint2*>(crow + 32 + rr * 8 + h8 * 4) = o1;
    }
  }
}

// ---------------- launcher ----------------
extern "C" void kernel_launch(void* const* d_in, const int* in_sizes, int n_in,
                              void* d_out, int out_size, void* d_ws, size_t ws_size,
                              hipStream_t stream) {
  (void)in_sizes; (void)n_in; (void)out_size; (void)ws_size;
  const float* x  = (const float*)d_in[0];
  const float* Wq = (const float*)d_in[1];
  const float* Wk = (const float*)d_in[2];
  const float* Wv = (const float*)d_in[3];
  const float* Wo = (const float*)d_in[4];
  const float* bo = (const float*)d_in[5];
  float* out = (float*)d_out;

  char* ws = (char*)d_ws;
  _Float16* xb    = (_Float16*)(ws);                 //  8 MB  x f16 [4096][1024]
  _Float16* wqkvt = (_Float16*)(ws + (8u  << 20));   //  6 MB  [Wq^T;Wk^T;Wv^T]
  _Float16* wot   = (_Float16*)(ws + (14u << 20));   //  2 MB  Wo^T
  _Float16* qkb   = (_Float16*)(ws + (16u << 20));   // 16 MB  QK [4096][2048]
  _Float16* vtb   = (_Float16*)(ws + (32u << 20));   //  8 MB  V^T [2][1024][2048]
  _Float16* ctx   = (_Float16*)(ws + (40u << 20));   //  8 MB  ctx [4096][1024]

  k_prep<<<8192, 256, 0, stream>>>(x, Wq, Wk, Wv, Wo, xb, wqkvt, wot);
  k_qkv<<<768, 256, 0, stream>>>(xb, wqkvt, qkb, vtb);
  k_attn_pair<<<512, 512, 0, stream>>>(qkb, vtb, ctx);
  k_out<<<512, 256, 0, stream>>>(ctx, wot, bo, out);
}

// Round 19
// 105.853 us; speedup vs baseline: 1.0656x; 1.0097x over previous
//
#include <hip/hip_runtime.h>
#include <stdint.h>

typedef _Float16 __attribute__((ext_vector_type(8))) f16x8;
typedef _Float16 __attribute__((ext_vector_type(4))) f16x4v;
typedef float __attribute__((ext_vector_type(4))) f32x4;
typedef float __attribute__((ext_vector_type(16))) f32x16;

__device__ __forceinline__ f32x4 mfma16(f16x8 a, f16x8 b, f32x4 c) {
  return __builtin_amdgcn_mfma_f32_16x16x32_f16(a, b, c, 0, 0, 0);
}
__device__ __forceinline__ f32x16 mfma32(f16x8 a, f16x8 b, f32x16 c) {
  return __builtin_amdgcn_mfma_f32_32x32x16_f16(a, b, c, 0, 0, 0);
}

// async global->LDS, 16B per lane. lds base wave-uniform; HW adds lane*16.
__device__ __forceinline__ void async16(void* lds, const void* g) {
  __builtin_amdgcn_global_load_lds((const __attribute__((address_space(1))) void*)g,
                                   (__attribute__((address_space(3))) void*)lds, 16, 0, 0);
}

__device__ __forceinline__ unsigned pk16(float a, float b) {
  return __builtin_bit_cast(unsigned, __builtin_amdgcn_cvt_pkrtz(a, b));
}

#define QK_PRESCALE 0.18033688011112042f  // (1/sqrt(64)) * log2(e)

// ---------------- prep: x->f16 cvt + 4 weight transposes, one launch ----------
__global__ __launch_bounds__(256) void k_prep(const float* __restrict__ x,
                                              const float* __restrict__ Wq,
                                              const float* __restrict__ Wk,
                                              const float* __restrict__ Wv,
                                              const float* __restrict__ Wo,
                                              _Float16* __restrict__ xb,
                                              _Float16* __restrict__ wqkvt,
                                              _Float16* __restrict__ wot) {
  __shared__ float tl[32][33];
  const int bid = blockIdx.x;
  if (bid < 4096) {                       // cvt: 4M f32 -> f16, float4/thread
    const int i = bid * 256 + threadIdx.x;
    const float4 v = reinterpret_cast<const float4*>(x)[i];
    f16x4v o = { (_Float16)v.x, (_Float16)v.y, (_Float16)v.z, (_Float16)v.w };
    reinterpret_cast<f16x4v*>(xb)[i] = o;
  } else {                                // transpose: 4096 blocks of 32x32
    const int i = bid - 4096;
    const int z = i >> 10, by = (i >> 5) & 31, bx = i & 31;
    const float* W = (z == 0) ? Wq : (z == 1) ? Wk : (z == 2) ? Wv : Wo;
    _Float16* dst = (z < 3) ? (wqkvt + ((size_t)z << 20)) : wot;
    const int c0 = bx * 32, r0 = by * 32;
    const int tx = threadIdx.x & 31, ty = threadIdx.x >> 5;  // 32 x 8
#pragma unroll
    for (int q = 0; q < 32; q += 8)
      tl[ty + q][tx] = W[(size_t)(r0 + ty + q) * 1024 + c0 + tx];
    __syncthreads();
#pragma unroll
    for (int q = 0; q < 32; q += 8)
      dst[(size_t)(c0 + ty + q) * 1024 + r0 + tx] = (_Float16)tl[tx][ty + q];
  }
}

// ---------------- fused QK-gemm + V-gemm, BK=64 (k_out mirror) ----------------
// 64x128 tile, BK=64, 4 waves (wave tile 32x64): per barrier 16 mfma + 12
// ds_read — same profile as k_out which measured ~660 TF. 16 barriers (vs 32
// at BK=32). Coalesced 8-chunk swizzled staging (validated): slot (row,qs)
// holds chunk qs^((row>>1)&7); 4 lanes/64B line. LDS 48KB -> 3 blk/CU;
// grid 1536 = 2 exact residency sweeps, uniform blocks.
__global__ __launch_bounds__(256) void k_qkv(const _Float16* __restrict__ xb,
                                             const _Float16* __restrict__ wqkvt,
                                             _Float16* __restrict__ qkb,
                                             _Float16* __restrict__ vtb) {
  __shared__ _Float16 As[2][4096];    // [64 rows][8 chunks][8 f16] swizzled
  __shared__ _Float16 Bs[2][8192];    // [128 rows][8 chunks][8 f16] swizzled
  const int bid = blockIdx.x;
  const _Float16 *A, *Bt;
  int tile_m, tile_n, role;
  if (bid < 1024) {                      // QK: M=4096 (64/t), N=2048 (128/t)
    const int swz = (bid & 7) * 128 + (bid >> 3);  // bijective XCD chunks
    tile_n = (swz & 15) * 128;
    tile_m = (swz >> 4) * 64;
    A = xb; Bt = wqkvt; role = 0;
  } else {                               // V: M=1024 dd (64/t), N=4096 (128/t)
    const int f = bid - 1024;
    const int swz = (f & 7) * 64 + (f >> 3);
    tile_n = (swz & 31) * 128;
    tile_m = (swz >> 5) * 64;
    A = wqkvt + (2u << 20); Bt = xb; role = 1;
  }
  const int K = 1024;
  const int t = threadIdx.x;
  const int w = t >> 6, lane = t & 63;
  const int c16 = lane & 15, g16 = lane >> 4;
  const int wm = w >> 1, wn = w & 1;               // 2M x 2N waves

  f32x4 acc[2][4] = {};

  const int rl = lane >> 3, qc = lane & 7;
  size_t aoff[2], boff[4];
#pragma unroll
  for (int q = 0; q < 2; ++q) {
    const int row = w * 16 + q * 8 + rl;
    aoff[q] = (size_t)(tile_m + row) * K + (qc ^ ((row >> 1) & 7)) * 8;
  }
#pragma unroll
  for (int q = 0; q < 4; ++q) {
    const int row = w * 32 + q * 8 + rl;
    boff[q] = (size_t)(tile_n + row) * K + (qc ^ ((row >> 1) & 7)) * 8;
  }

  auto stage = [&](int buf, int k0) {
#pragma unroll
    for (int q = 0; q < 2; ++q)
      async16(&As[buf][(w * 128 + q * 64) * 8], A + aoff[q] + k0);
#pragma unroll
    for (int q = 0; q < 4; ++q)
      async16(&Bs[buf][(w * 256 + q * 64) * 8], Bt + boff[q] + k0);
  };

  stage(0, 0);
  for (int kt = 0; kt < 16; ++kt) {
    const int buf = kt & 1;
    __syncthreads();                     // stage(kt) drained; prev reads done
    if (kt + 1 < 16) stage(buf ^ 1, (kt + 1) << 6);
#pragma unroll
    for (int ks = 0; ks < 2; ++ks) {     // two K=32 halves
      const int c = ks * 4 + g16;        // k-chunk 0..7
      f16x8 af[2], bf[4];
#pragma unroll
      for (int i = 0; i < 2; ++i) {
        const int r = wm * 32 + i * 16 + c16;
        af[i] = *reinterpret_cast<const f16x8*>(&As[buf][(r * 8 + (c ^ ((r >> 1) & 7))) * 8]);
      }
#pragma unroll
      for (int j = 0; j < 4; ++j) {
        const int r = wn * 64 + j * 16 + c16;
        bf[j] = *reinterpret_cast<const f16x8*>(&Bs[buf][(r * 8 + (c ^ ((r >> 1) & 7))) * 8]);
      }
#pragma unroll
      for (int i = 0; i < 2; ++i)
#pragma unroll
        for (int j = 0; j < 4; ++j) acc[i][j] = mfma16(af[i], bf[j], acc[i][j]);
    }
  }

  // D layout: col = lane&15, row = (lane>>4)*4 + reg
#pragma unroll
  for (int i = 0; i < 2; ++i) {
#pragma unroll
    for (int j = 0; j < 4; ++j) {
      const int col = tile_n + wn * 64 + j * 16 + c16;
#pragma unroll
      for (int r = 0; r < 4; ++r) {
        const int row = tile_m + wm * 32 + i * 16 + g16 * 4 + r;
        float v = acc[i][j][r];
        if (role == 0) {
          if (col < 1024) v *= QK_PRESCALE;    // fold softmax scale into Q
          qkb[(size_t)row * 2048 + col] = (_Float16)v;
        } else {
          vtb[((size_t)(col >> 11) << 21) + (size_t)row * 2048 + (col & 2047)] = (_Float16)v;
        }
      }
    }
  }
}

// ---------------- O-gemm: BK=64, coalesced swizzled staging (R17 proven) ------
__global__ __launch_bounds__(256) void k_out(const _Float16* __restrict__ ctx,
                                             const _Float16* __restrict__ wot,
                                             const float* __restrict__ bias,
                                             float* __restrict__ out) {
  __shared__ _Float16 As[2][8192];    // [128 rows][8 chunks][8 f16] swizzled
  __shared__ _Float16 Bs[2][4096];    // [64 rows][8 chunks][8 f16] swizzled
  const int bid = blockIdx.x;                    // 512
  const int swz = (bid & 7) * 64 + (bid >> 3);
  const int tile_n = (swz & 15) * 64;
  const int tile_m = (swz >> 4) * 128;
  const int K = 1024;
  const int t = threadIdx.x;
  const int w = t >> 6, lane = t & 63;
  const int c16 = lane & 15, g16 = lane >> 4;
  const int wr = (w >> 1) * 64, wc = (w & 1) * 32;

  f32x4 acc[4][2] = {};

  const int rl = lane >> 3, qc = lane & 7;
  size_t aoff[4], boff[2];
#pragma unroll
  for (int q = 0; q < 4; ++q) {
    const int row = w * 32 + q * 8 + rl;
    aoff[q] = (size_t)(tile_m + row) * K + (qc ^ ((row >> 1) & 7)) * 8;
  }
#pragma unroll
  for (int q = 0; q < 2; ++q) {
    const int row = w * 16 + q * 8 + rl;
    boff[q] = (size_t)(tile_n + row) * K + (qc ^ ((row >> 1) & 7)) * 8;
  }

  auto stage = [&](int buf, int k0) {
#pragma unroll
    for (int q = 0; q < 4; ++q)
      async16(&As[buf][(w * 256 + q * 64) * 8], ctx + aoff[q] + k0);
#pragma unroll
    for (int q = 0; q < 2; ++q)
      async16(&Bs[buf][(w * 128 + q * 64) * 8], wot + boff[q] + k0);
  };

  stage(0, 0);
  for (int kt = 0; kt < 16; ++kt) {
    const int buf = kt & 1;
    __syncthreads();
    if (kt + 1 < 16) stage(buf ^ 1, (kt + 1) << 6);
#pragma unroll
    for (int ks = 0; ks < 2; ++ks) {
      const int c = ks * 4 + g16;
      f16x8 af[4], bf[2];
#pragma unroll
      for (int i = 0; i < 4; ++i) {
        const int r = wr + i * 16 + c16;
        af[i] = *reinterpret_cast<const f16x8*>(&As[buf][(r * 8 + (c ^ ((r >> 1) & 7))) * 8]);
      }
#pragma unroll
      for (int j = 0; j < 2; ++j) {
        const int r = wc + j * 16 + c16;
        bf[j] = *reinterpret_cast<const f16x8*>(&Bs[buf][(r * 8 + (c ^ ((r >> 1) & 7))) * 8]);
      }
#pragma unroll
      for (int i = 0; i < 4; ++i)
#pragma unroll
        for (int j = 0; j < 2; ++j) acc[i][j] = mfma16(af[i], bf[j], acc[i][j]);
    }
  }

#pragma unroll
  for (int i = 0; i < 4; ++i) {
#pragma unroll
    for (int j = 0; j < 2; ++j) {
      const int col = tile_n + wc + j * 16 + c16;
#pragma unroll
      for (int r = 0; r < 4; ++r) {
        const int row = tile_m + wr + i * 16 + g16 * 4 + r;
        out[(size_t)row * 1024 + col] = acc[i][j][r] + bias[col];
      }
    }
  }
}

// ---------------- causal attention: paired block, COALESCED K/V staging -------
// (unchanged — validated)
__global__ __launch_bounds__(512, 4) void k_attn_pair(const _Float16* __restrict__ qk,
                                                      const _Float16* __restrict__ vt,
                                                      _Float16* __restrict__ ctx) {
  const int fid = blockIdx.x;                 // 512 blocks = 2/CU, all resident
  const int lid = fid & 255, half = fid >> 8;
  const int xcd = lid & 7, g = lid >> 3;      // g in [0,32)
  const int bh = xcd + 8 * (g & 3);           // 4 bh per XCD -> K/V/Q L2-resident
  const int p = g >> 2;                       // [0,8)
  const int pr = half ? (15 - p) : p;         // CU slot pairs pr=p with 15-p: uniform
  const int a = 31 - pr;
  const int b = bh >> 4, h = bh & 15;

  const int t = threadIdx.x, w = t >> 6, lane = t & 63;
  const int li = lane & 31, h8 = lane >> 5;
  const int qs = w >> 1, par = w & 1;
  const int qt = (qs < 2) ? (2 * a + (qs & 1)) : (2 * pr + (qs & 1));

  const _Float16* Qp = qk + ((size_t)b << 22) + (h << 6);
  const _Float16* Kp = Qp + 1024;
  const _Float16* Vt = vt + ((((size_t)b << 10) + (size_t)(h << 6)) << 11);

  __shared__ _Float16 Kl[2][4096];   // [cg2][row64][cc4][8f16] swizzled
  __shared__ _Float16 Vl[2][4096];   // [cg2][d64][cc4][8f16]  swizzled
  __shared__ _Float16 Cb[4][32][68]; // pair-combine O (padded rows)
  __shared__ float Cl[4][32];        // pair-combine l

  const int qrow = qt * 32 + li;
  f16x8 qf[4];
#pragma unroll
  for (int mm = 0; mm < 4; ++mm)
    qf[mm] = *reinterpret_cast<const f16x8*>(Qp + (size_t)qrow * 2048 + mm * 16 + h8 * 8);

  // coalesced stage: wave w -> rows (w&3)*16..+15, chunk-group cg=w>>2
  const int srg = w & 3, scg = w >> 2;
  const int srl = lane >> 2;                           // row within group
  const int srowk = srg * 16 + srl;                    // tile row 0..63
  const int sc = scg * 4 + ((lane & 3) ^ ((srl >> 1) & 3));  // pre-swz 16B chunk
  auto stage = [&](int buf, int s) {
    const int kb = s << 6;
    async16(&Kl[buf][(scg * 256 + srg * 64) * 8],
            Kp + (size_t)(kb + srowk) * 2048 + sc * 8);
    async16(&Vl[buf][(scg * 256 + srg * 64) * 8],
            Vt + (size_t)srowk * 2048 + kb + sc * 8);
  };

  const int rkey = (li >> 1) & 3;                      // read-side swizzle key

  f32x16 oa0, oa1;
#pragma unroll
  for (int r = 0; r < 16; ++r) { oa0[r] = 0.f; oa1[r] = 0.f; }
  float la0 = 0.f, la1 = 0.f;

  stage(0, 0);
  for (int s = 0; s <= a; ++s) {
    const int buf = s & 1;
    __syncthreads();                    // staged buf ready; prev buf reads done
    if (s < a) stage(buf ^ 1, s + 1);   // prefetch overlaps compute
    const int j = 2 * s + par;
    if (j <= qt) {
      f32x16 st;
#pragma unroll
      for (int r = 0; r < 16; ++r) st[r] = 0.f;
#pragma unroll
      for (int mm = 0; mm < 4; ++mm) {
        const int c = mm * 2 + h8;
        const int slot = ((c >> 2) << 8) + (par * 32 + li) * 4 + ((c & 3) ^ rkey);
        const f16x8 kf = *reinterpret_cast<const f16x8*>(&Kl[buf][slot * 8]);
        st = mfma32(kf, qf[mm], st);
      }
      if (j == qt) {  // diagonal sub-tile: causal mask
#pragma unroll
        for (int r = 0; r < 16; ++r) {
          const int kloc = (r & 3) + ((r >> 2) << 3) + (h8 << 2);
          if (kloc > li) st[r] = -1000.f;
        }
      }
      unsigned G[8];
#pragma unroll
      for (int jj = 0; jj < 8; ++jj) {
        const float p0 = __builtin_amdgcn_exp2f(st[2 * jj]);
        const float p1 = __builtin_amdgcn_exp2f(st[2 * jj + 1]);
        if (jj & 1) la1 += p0 + p1; else la0 += p0 + p1;
        G[jj] = pk16(p0, p1);
      }
#pragma unroll
      for (int chunk = 0; chunk < 2; ++chunk) {
        const unsigned g0 = G[chunk * 4 + 0], g1 = G[chunk * 4 + 1];
        const unsigned g2 = G[chunk * 4 + 2], g3 = G[chunk * 4 + 3];
        const unsigned s02 = __shfl_xor(h8 ? g0 : g2, 32);
        const unsigned s13 = __shfl_xor(h8 ? g1 : g3, 32);
        union { unsigned u[4]; f16x8 v; } pb;
        pb.u[0] = h8 ? s02 : g0;
        pb.u[1] = h8 ? s13 : g1;
        pb.u[2] = h8 ? g2 : s02;
        pb.u[3] = h8 ? g3 : s13;
        const int c0 = par * 4 + chunk * 2 + h8;
        const int sv0 = ((c0 >> 2) << 8) + li * 4 + ((c0 & 3) ^ rkey);
        const int sv1 = sv0 + 128;     // row +32, same key
        const f16x8 vf0 = *reinterpret_cast<const f16x8*>(&Vl[buf][sv0 * 8]);
        const f16x8 vf1 = *reinterpret_cast<const f16x8*>(&Vl[buf][sv1 * 8]);
        oa0 = mfma32(vf0, pb.v, oa0);
        oa1 = mfma32(vf1, pb.v, oa1);
      }
    }
  }

  float lsum = la0 + la1;
  lsum += __shfl_xor(lsum, 32);
  __syncthreads();                       // last compute reads done before Cb reuse
  if (par) {
#pragma unroll
    for (int rr = 0; rr < 4; ++rr) {
      uint2 p0, p1;
      p0.x = pk16(oa0[rr * 4 + 0], oa0[rr * 4 + 1]);
      p0.y = pk16(oa0[rr * 4 + 2], oa0[rr * 4 + 3]);
      p1.x = pk16(oa1[rr * 4 + 0], oa1[rr * 4 + 1]);
      p1.y = pk16(oa1[rr * 4 + 2], oa1[rr * 4 + 3]);
      *reinterpret_cast<uint2*>(&Cb[qs][li][rr * 8 + h8 * 4]) = p0;
      *reinterpret_cast<uint2*>(&Cb[qs][li][32 + rr * 8 + h8 * 4]) = p1;
    }
    if (!h8) Cl[qs][li] = lsum;
  }
  __syncthreads();
  if (!par) {
    const float lt = lsum + Cl[qs][li];
    const float rl = 1.f / lt;
    _Float16* crow = ctx + ((size_t)(b * 2048 + qrow) << 10) + h * 64;
#pragma unroll
    for (int rr = 0; rr < 4; ++rr) {
      const f16x4v q0 = *reinterpret_cast<const f16x4v*>(&Cb[qs][li][rr * 8 + h8 * 4]);
      const f16x4v q1 = *reinterpret_cast<const f16x4v*>(&Cb[qs][li][32 + rr * 8 + h8 * 4]);
      uint2 o0, o1;
      o0.x = pk16((oa0[rr * 4 + 0] + (float)q0[0]) * rl, (oa0[rr * 4 + 1] + (float)q0[1]) * rl);
      o0.y = pk16((oa0[rr * 4 + 2] + (float)q0[2]) * rl, (oa0[rr * 4 + 3] + (float)q0[3]) * rl);
      o1.x = pk16((oa1[rr * 4 + 0] + (float)q1[0]) * rl, (oa1[rr * 4 + 1] + (float)q1[1]) * rl);
      o1.y = pk16((oa1[rr * 4 + 2] + (float)q1[2]) * rl, (oa1[rr * 4 + 3] + (float)q1[3]) * rl);
      *reinterpret_cast<uint2*>(crow + rr * 8 + h8 * 4) = o0;
      *reinterpret_cast<uint2*>(crow + 32 + rr * 8 + h8 * 4) = o1;
    }
  }
}

// ---------------- launcher ----------------
extern "C" void kernel_launch(void* const* d_in, const int* in_sizes, int n_in,
                              void* d_out, int out_size, void* d_ws, size_t ws_size,
                              hipStream_t stream) {
  (void)in_sizes; (void)n_in; (void)out_size; (void)ws_size;
  const float* x  = (const float*)d_in[0];
  const float* Wq = (const float*)d_in[1];
  const float* Wk = (const float*)d_in[2];
  const float* Wv = (const float*)d_in[3];
  const float* Wo = (const float*)d_in[4];
  const float* bo = (const float*)d_in[5];
  float* out = (float*)d_out;

  char* ws = (char*)d_ws;
  _Float16* xb    = (_Float16*)(ws);                 //  8 MB  x f16 [4096][1024]
  _Float16* wqkvt = (_Float16*)(ws + (8u  << 20));   //  6 MB  [Wq^T;Wk^T;Wv^T]
  _Float16* wot   = (_Float16*)(ws + (14u << 20));   //  2 MB  Wo^T
  _Float16* qkb   = (_Float16*)(ws + (16u << 20));   // 16 MB  QK [4096][2048]
  _Float16* vtb   = (_Float16*)(ws + (32u << 20));   //  8 MB  V^T [2][1024][2048]
  _Float16* ctx   = (_Float16*)(ws + (40u << 20));   //  8 MB  ctx [4096][1024]

  k_prep<<<8192, 256, 0, stream>>>(x, Wq, Wk, Wv, Wo, xb, wqkvt, wot);
  k_qkv<<<1536, 256, 0, stream>>>(xb, wqkvt, qkb, vtb);
  k_attn_pair<<<512, 512, 0, stream>>>(qkb, vtb, ctx);
  k_out<<<512, 256, 0, stream>>>(ctx, wot, bo, out);
}